// Round 3
// baseline (253.310 us; speedup 1.0000x reference)
//
#include <hip/hip_runtime.h>
#include <hip/hip_bf16.h>

#define IMG 28
#define OHW 26
#define NPIX 676
#define KT_N 22            // k-tiles of 32 -> K=704 padded
#define NH 200
#define NT_N 14            // n-tiles of 16 -> N=224 padded
#define NOUT 10
#define HS 232             // h LDS row stride in bf16 elems (224 + 8; 232*2=464=29*16 -> 16B aligned rows)

typedef __attribute__((ext_vector_type(8))) short bf16x8;
typedef __attribute__((ext_vector_type(4))) float f32x4;

static __device__ __forceinline__ unsigned short bf16_bits(float v) {
    __hip_bfloat16 b = __float2bfloat16(v);
    return *(unsigned short*)&b;
}

// ---------------- pack w0/w1 into MFMA-fragment-ready bf16 ----------------
// B_frag[nt][kt][lane][j] = w0[nt*16 + (lane&15)][kt*32 + (lane>>4)*8 + j] (0-padded)
// W1_frag[kt][lane][j]    = w1[lane&15][kt*32 + (lane>>4)*8 + j]          (0-padded)
__global__ void pack_weights(const float* __restrict__ w0, const float* __restrict__ w1,
                             __hip_bfloat16* __restrict__ Bf, __hip_bfloat16* __restrict__ W1f) {
    int idx = blockIdx.x * blockDim.x + threadIdx.x;
    const int nb = NT_N * KT_N * 512;  // 157696
    if (idx < nb) {
        int j = idx & 7, L = (idx >> 3) & 63, kt = (idx >> 9) % KT_N, nt = idx / (KT_N * 512);
        int n = nt * 16 + (L & 15), k = kt * 32 + ((L >> 4) << 3) + j;
        float v = (n < NH && k < NPIX) ? w0[n * NPIX + k] : 0.f;
        Bf[idx] = __float2bfloat16(v);
    } else if (idx < nb + 7 * 512) {
        int r = idx - nb;
        int j = r & 7, L = (r >> 3) & 63, kt = r >> 9;
        int n = L & 15, k = kt * 32 + ((L >> 4) << 3) + j;
        float v = (n < NOUT && k < NH) ? w1[n * NH + k] : 0.f;
        W1f[r] = __float2bfloat16(v);
    }
}

// ---------------- conv: wave per image, LDS-staged, fragment-ready output ----------------
// A_frag[mt][kt][lane][j] with lane = q*16+im: value = conv(img=mt*16+im, k=kt*32+q*8+j)
__global__ __launch_bounds__(256) void conv_kernel(const float* __restrict__ x,
                                                   const float* __restrict__ cw,
                                                   __hip_bfloat16* __restrict__ Af) {
    __shared__ float simg[4][800];  // 784 floats per wave's image
    const int tid = threadIdx.x, wave = tid >> 6, L = tid & 63;
    const int img = blockIdx.x * 4 + wave;

    const float k00 = cw[0], k01 = cw[1], k02 = cw[2];
    const float k10 = cw[3], k11 = cw[4], k12 = cw[5];
    const float k20 = cw[6], k21 = cw[7], k22 = cw[8];

    // coalesced image load: 196 float4
    {
        const float4* src = (const float4*)(x + (size_t)img * (IMG * IMG));
        float4* dst = (float4*)simg[wave];
        for (int c4 = L; c4 < 196; c4 += 64) dst[c4] = src[c4];
    }
    __syncthreads();

    const float* buf = simg[wave];
    const int mt = img >> 4, im = img & 15;
    unsigned short* abase = (unsigned short*)Af + (size_t)mt * (KT_N * 512);

    // output pairs p = 2*pp, pp = L + 64t ; pairs 338..351 are zero padding (k 676..703)
    for (int t = 0; t < 6; ++t) {
        int pp = L + (t << 6);
        if (pp >= 352) continue;
        int p = pp * 2;
        float o0 = 0.f, o1 = 0.f;
        if (p < NPIX) {
            int r = p / OHW, c = p - r * OHW;  // c even, <= 24
            const float* bp = buf + r * IMG + c;
            float2 r0a = *(const float2*)(bp),            r0b = *(const float2*)(bp + 2);
            float2 r1a = *(const float2*)(bp + IMG),      r1b = *(const float2*)(bp + IMG + 2);
            float2 r2a = *(const float2*)(bp + 2 * IMG),  r2b = *(const float2*)(bp + 2 * IMG + 2);
            o0 = r0a.x * k00 + r0a.y * k01 + r0b.x * k02
               + r1a.x * k10 + r1a.y * k11 + r1b.x * k12
               + r2a.x * k20 + r2a.y * k21 + r2b.x * k22;
            o1 = r0a.y * k00 + r0b.x * k01 + r0b.y * k02
               + r1a.y * k10 + r1b.x * k11 + r1b.y * k12
               + r2a.y * k20 + r2b.x * k21 + r2b.y * k22;
        }
        unsigned u = (unsigned)bf16_bits(o0) | ((unsigned)bf16_bits(o1) << 16);
        int kt = p >> 5, q = (p >> 3) & 3, j = p & 7;  // j even
        *(unsigned*)(abase + kt * 512 + (q * 16 + im) * 8 + j) = u;
    }
}

// ---------------- GEMM: FC0 (MFMA) + relu/bias + FC1 (MFMA) ----------------
__global__ __launch_bounds__(256, 3) void gemm_kernel(
    const __hip_bfloat16* __restrict__ Af, const __hip_bfloat16* __restrict__ Bf,
    const __hip_bfloat16* __restrict__ W1f,
    const float* __restrict__ b0v, const float* __restrict__ b1v,
    float* __restrict__ out) {
    __shared__ __hip_bfloat16 H[64 * HS];  // 29696 B

    const int tid = threadIdx.x, w = tid >> 6, L = tid & 63;
    const int lm = L & 15, q = L >> 4;
    const int gm = blockIdx.x * 4 + w;  // global m-sub (16 images)

    f32x4 acc[NT_N];
#pragma unroll
    for (int t = 0; t < NT_N; ++t) acc[t] = (f32x4){0.f, 0.f, 0.f, 0.f};

    const bf16x8* ap = (const bf16x8*)Af + (size_t)gm * (KT_N * 64) + L;
    const bf16x8* bp = (const bf16x8*)Bf + L;

    for (int kt = 0; kt < KT_N; ++kt) {
        bf16x8 a = ap[kt * 64];
#pragma unroll
        for (int t = 0; t < NT_N; ++t) {
            bf16x8 b = bp[(t * KT_N + kt) * 64];
            acc[t] = __builtin_amdgcn_mfma_f32_16x16x32_bf16(a, b, acc[t], 0, 0, 0);
        }
    }

    // epilogue: h = relu(acc + b0) -> LDS rows [w*16, w*16+16)
#pragma unroll
    for (int t = 0; t < NT_N; ++t) {
        int n = t * 16 + lm;
        float bias = (n < NH) ? b0v[n] : 0.f;
#pragma unroll
        for (int r = 0; r < 4; ++r) {
            float v = acc[t][r] + bias;
            v = v > 0.f ? v : 0.f;
            H[(w * 16 + q * 4 + r) * HS + n] = __float2bfloat16(v);
        }
    }
    __syncthreads();

    // FC1: 16x16x32 MFMA over k=224 (7 k-tiles); A from H (own wave's rows), B = W1_frag
    f32x4 o = (f32x4){0.f, 0.f, 0.f, 0.f};
    const __hip_bfloat16* hrow = H + (w * 16 + lm) * HS;
#pragma unroll
    for (int kt = 0; kt < 7; ++kt) {
        bf16x8 a = *(const bf16x8*)(hrow + kt * 32 + q * 8);
        bf16x8 b = ((const bf16x8*)W1f)[kt * 64 + L];
        o = __builtin_amdgcn_mfma_f32_16x16x32_bf16(a, b, o, 0, 0, 0);
    }
    if (lm < NOUT) {
        float bias = b1v[lm];
        int img0 = blockIdx.x * 64 + w * 16;
#pragma unroll
        for (int r = 0; r < 4; ++r) {
            out[(size_t)(img0 + q * 4 + r) * NOUT + lm] = o[r] + bias;
        }
    }
}

extern "C" void kernel_launch(void* const* d_in, const int* in_sizes, int n_in,
                              void* d_out, int out_size, void* d_ws, size_t ws_size,
                              hipStream_t stream) {
    const float* x   = (const float*)d_in[0];
    const float* cw  = (const float*)d_in[1];
    const float* w0  = (const float*)d_in[2];
    const float* b0  = (const float*)d_in[3];
    const float* w1  = (const float*)d_in[4];
    const float* b1  = (const float*)d_in[5];
    float* out = (float*)d_out;

    // workspace layout
    __hip_bfloat16* Af  = (__hip_bfloat16*)d_ws;               // 2048*22*512 elems = 46,137,344 B
    __hip_bfloat16* Bf  = Af + (size_t)2048 * KT_N * 512;      // 157,696 elems = 315,392 B
    __hip_bfloat16* W1f = Bf + NT_N * KT_N * 512;              // 3,584 elems = 7,168 B

    const int pack_elems = NT_N * KT_N * 512 + 7 * 512;
    pack_weights<<<(pack_elems + 255) / 256, 256, 0, stream>>>(w0, w1, Bf, W1f);

    conv_kernel<<<32768 / 4, 256, 0, stream>>>(x, cw, Af);

    gemm_kernel<<<32768 / 64, 256, 0, stream>>>(Af, Bf, W1f, b0, b1, out);
}

// Round 4
// 202.017 us; speedup vs baseline: 1.2539x; 1.2539x over previous
//
#include <hip/hip_runtime.h>
#include <hip/hip_bf16.h>

#define IMG 28
#define OHW 26
#define NPIX 676           // 26*26
#define KT_N 22            // k-tiles of 32 -> K padded to 704
#define NT_N 13            // n-tiles of 16 -> N padded to 208
#define NH 200
#define NOUT 10
#define MT 32              // images per block
#define ASTRIDE 712        // bf16 elems per LDS A row (704 + 8 pad -> free 2-way conflicts)
#define HSTRIDE 208        // fp32 elems per LDS h row (208*4B rows, 16B aligned)

typedef __attribute__((ext_vector_type(8))) short bf16x8;
typedef __attribute__((ext_vector_type(4))) float f32x4;

static __device__ __forceinline__ unsigned short bf16_bits(float v) {
    __hip_bfloat16 b = __float2bfloat16(v);
    return *(unsigned short*)&b;
}

// --- pack w0 (200x676 fp32) -> MFMA-fragment-ordered bf16 ---
// Bf[nt][kt][lane][j] = w0[nt*16 + (lane&15)][kt*32 + (lane>>4)*8 + j], 0-padded
__global__ void pack_weights(const float* __restrict__ w0,
                             __hip_bfloat16* __restrict__ Bf) {
    int idx = blockIdx.x * blockDim.x + threadIdx.x;
    if (idx >= NT_N * KT_N * 512) return;
    int j = idx & 7, L = (idx >> 3) & 63, kt = (idx >> 9) % KT_N, nt = idx / (KT_N * 512);
    int n = nt * 16 + (L & 15), k = kt * 32 + ((L >> 4) << 3) + j;
    float v = (n < NH && k < NPIX) ? w0[n * NPIX + k] : 0.f;
    Bf[idx] = __float2bfloat16(v);
}

__global__ __launch_bounds__(512, 6) void fused_mlp_kernel(
    const float* __restrict__ x,            // [32768, 784]
    const float* __restrict__ cw,           // [3,3]
    const __hip_bfloat16* __restrict__ Bf,  // fragment-packed w0
    const float* __restrict__ b0,           // [200]
    const float* __restrict__ w1,           // [10, 200]
    const float* __restrict__ b1,           // [10]
    float* __restrict__ out)                // [32768, 10]
{
    __shared__ __align__(16) char lds_raw[MT * ASTRIDE * 2]; // 45568 B
    __hip_bfloat16* A = (__hip_bfloat16*)lds_raw;            // [MT][ASTRIDE] bf16
    float* H = (float*)lds_raw;                              // [MT][HSTRIDE] fp32 (overlays A)

    const int tid = threadIdx.x;
    const int img0 = blockIdx.x * MT;

    const float k00 = cw[0], k01 = cw[1], k02 = cw[2];
    const float k10 = cw[3], k11 = cw[4], k12 = cw[5];
    const float k20 = cw[6], k21 = cw[7], k22 = cw[8];

    // ---- zero the K pad region (cols 676..711) ----
    for (int idx = tid; idx < MT * (ASTRIDE - NPIX); idx += 512) {
        int i = idx / (ASTRIDE - NPIX);
        int c = idx - i * (ASTRIDE - NPIX);
        ((unsigned short*)A)[i * ASTRIDE + NPIX + c] = 0;
    }

    // ---- conv 3x3 valid: one task = (image, output row); float4 row loads ----
    for (int task = tid; task < MT * OHW; task += 512) {
        int img  = task / OHW;
        int orow = task - img * OHW;
        const float* base = x + (size_t)(img0 + img) * (IMG * IMG) + orow * IMG;

        float4 r0[7], r1[7], r2[7];
#pragma unroll
        for (int j = 0; j < 7; ++j) {
            r0[j] = ((const float4*)base)[j];
            r1[j] = ((const float4*)(base + IMG))[j];
            r2[j] = ((const float4*)(base + 2 * IMG))[j];
        }
        const float* a0r = (const float*)r0;
        const float* a1r = (const float*)r1;
        const float* a2r = (const float*)r2;

        unsigned short obits[OHW];
#pragma unroll
        for (int c = 0; c < OHW; ++c) {
            float acc = a0r[c] * k00 + a0r[c + 1] * k01 + a0r[c + 2] * k02
                      + a1r[c] * k10 + a1r[c + 1] * k11 + a1r[c + 2] * k12
                      + a2r[c] * k20 + a2r[c + 1] * k21 + a2r[c + 2] * k22;
            obits[c] = bf16_bits(acc);
        }
        unsigned* dst = (unsigned*)(A + img * ASTRIDE + orow * OHW); // 4B aligned (52B stride)
#pragma unroll
        for (int c2 = 0; c2 < 13; ++c2) {
            dst[c2] = (unsigned)obits[2 * c2] | ((unsigned)obits[2 * c2 + 1] << 16);
        }
    }
    __syncthreads();

    // ---- FC0 via MFMA 16x16x32 bf16 ----
    // 8 waves own disjoint n-tiles {2,2,2,2,2,1,1,1}; each wave does both m-tiles,
    // so every coalesced B-frag load feeds 2 MFMAs.
    const int wave = tid >> 6;
    const int lane = tid & 63;
    const int lm   = lane & 15;
    const int q    = lane >> 4;
    const int ntbase = (wave < 5) ? wave * 2 : 10 + (wave - 5);
    const int ntn    = (wave < 5) ? 2 : 1;

    f32x4 acc[2][2];
#pragma unroll
    for (int m = 0; m < 2; ++m)
#pragma unroll
        for (int t = 0; t < 2; ++t) acc[m][t] = (f32x4){0.f, 0.f, 0.f, 0.f};

    {
        const __hip_bfloat16* a0 = A + lm * ASTRIDE + q * 8;
        const __hip_bfloat16* a1 = A + (16 + lm) * ASTRIDE + q * 8;
        const bf16x8* bb = (const bf16x8*)Bf + (size_t)ntbase * KT_N * 64 + lane;

        if (ntn == 2) {
            for (int kt = 0; kt < KT_N; ++kt) {
                bf16x8 af0 = *(const bf16x8*)(a0 + kt * 32);
                bf16x8 af1 = *(const bf16x8*)(a1 + kt * 32);
                bf16x8 bf0 = bb[kt * 64];
                bf16x8 bf1 = bb[(KT_N + kt) * 64];
                acc[0][0] = __builtin_amdgcn_mfma_f32_16x16x32_bf16(af0, bf0, acc[0][0], 0, 0, 0);
                acc[1][0] = __builtin_amdgcn_mfma_f32_16x16x32_bf16(af1, bf0, acc[1][0], 0, 0, 0);
                acc[0][1] = __builtin_amdgcn_mfma_f32_16x16x32_bf16(af0, bf1, acc[0][1], 0, 0, 0);
                acc[1][1] = __builtin_amdgcn_mfma_f32_16x16x32_bf16(af1, bf1, acc[1][1], 0, 0, 0);
            }
        } else {
            for (int kt = 0; kt < KT_N; ++kt) {
                bf16x8 af0 = *(const bf16x8*)(a0 + kt * 32);
                bf16x8 af1 = *(const bf16x8*)(a1 + kt * 32);
                bf16x8 bf0 = bb[kt * 64];
                acc[0][0] = __builtin_amdgcn_mfma_f32_16x16x32_bf16(af0, bf0, acc[0][0], 0, 0, 0);
                acc[1][0] = __builtin_amdgcn_mfma_f32_16x16x32_bf16(af1, bf0, acc[1][0], 0, 0, 0);
            }
        }
    }
    __syncthreads(); // all waves done reading A before H overwrites it

    // ---- epilogue: h = relu(acc + b0) -> LDS ----
#pragma unroll
    for (int t = 0; t < 2; ++t) {
        if (t < ntn) {
            int n = (ntbase + t) * 16 + lm;
            if (n < NH) {
                float bv = b0[n];
#pragma unroll
                for (int m = 0; m < 2; ++m) {
#pragma unroll
                    for (int r = 0; r < 4; ++r) {
                        int mm = m * 16 + q * 4 + r;
                        float v = acc[m][t][r] + bv;
                        H[mm * HSTRIDE + n] = v > 0.f ? v : 0.f;
                    }
                }
            }
        }
    }
    __syncthreads();

    // ---- FC1: out = h @ w1.T + b1 (fp32 VALU, 320 results/block) ----
    if (tid < MT * NOUT) {
        int i = tid / NOUT;
        int j = tid - i * NOUT;
        const float4* hrow = (const float4*)(H + i * HSTRIDE);
        const float4* wrow = (const float4*)(w1 + j * NH);
        float s = b1[j];
        float4 accv = {0.f, 0.f, 0.f, 0.f};
#pragma unroll 10
        for (int n = 0; n < NH / 4; ++n) {
            float4 h4 = hrow[n];
            float4 w4 = wrow[n];
            accv.x += h4.x * w4.x;
            accv.y += h4.y * w4.y;
            accv.z += h4.z * w4.z;
            accv.w += h4.w * w4.w;
        }
        s += (accv.x + accv.y) + (accv.z + accv.w);
        out[(size_t)(img0 + i) * NOUT + j] = s;
    }
}

extern "C" void kernel_launch(void* const* d_in, const int* in_sizes, int n_in,
                              void* d_out, int out_size, void* d_ws, size_t ws_size,
                              hipStream_t stream) {
    const float* x   = (const float*)d_in[0];
    const float* cw  = (const float*)d_in[1];
    const float* w0  = (const float*)d_in[2];
    const float* b0  = (const float*)d_in[3];
    const float* w1  = (const float*)d_in[4];
    const float* b1  = (const float*)d_in[5];
    float* out = (float*)d_out;

    __hip_bfloat16* Bf = (__hip_bfloat16*)d_ws; // 13*22*512*2 = 292,864 B

    const int pack_elems = NT_N * KT_N * 512;
    pack_weights<<<(pack_elems + 255) / 256, 256, 0, stream>>>(w0, Bf);

    fused_mlp_kernel<<<32768 / MT, 512, 0, stream>>>(x, cw, Bf, b0, w1, b1, out);
}

// Round 5
// 190.497 us; speedup vs baseline: 1.3297x; 1.0605x over previous
//
#include <hip/hip_runtime.h>
#include <hip/hip_bf16.h>

#define IMG 28
#define OHW 26
#define NPIX 676           // 26*26
#define KT_N 22            // k-tiles of 32 -> K padded to 704
#define NT_N 13            // n-tiles of 16 -> N padded to 208
#define NH 200
#define NOUT 10
#define MT 32              // images per block
#define ASTRIDE 712        // bf16 elems per LDS A row (704 + 8 pad -> free 2-way conflicts)
#define HSTRIDE 208        // fp32 elems per LDS h row
#define SLAB 800           // fp32 elems per wave image slab (784 + 16 pad)

typedef __attribute__((ext_vector_type(8))) short bf16x8;
typedef __attribute__((ext_vector_type(4))) float f32x4;

static __device__ __forceinline__ unsigned short bf16_bits(float v) {
    __hip_bfloat16 b = __float2bfloat16(v);
    return *(unsigned short*)&b;
}

// --- pack w0 (200x676 fp32) -> MFMA-fragment-ordered bf16 ---
// Bf[nt][kt][lane][j] = w0[nt*16 + (lane&15)][kt*32 + (lane>>4)*8 + j], 0-padded
__global__ void pack_weights(const float* __restrict__ w0,
                             __hip_bfloat16* __restrict__ Bf) {
    int idx = blockIdx.x * blockDim.x + threadIdx.x;
    if (idx >= NT_N * KT_N * 512) return;
    int j = idx & 7, L = (idx >> 3) & 63, kt = (idx >> 9) % KT_N, nt = idx / (KT_N * 512);
    int n = nt * 16 + (L & 15), k = kt * 32 + ((L >> 4) << 3) + j;
    float v = (n < NH && k < NPIX) ? w0[n * NPIX + k] : 0.f;
    Bf[idx] = __float2bfloat16(v);
}

__global__ __launch_bounds__(512, 4) void fused_mlp_kernel(
    const float* __restrict__ x,            // [32768, 784]
    const float* __restrict__ cw,           // [3,3]
    const __hip_bfloat16* __restrict__ Bf,  // fragment-packed w0
    const float* __restrict__ b0,           // [200]
    const float* __restrict__ w1,           // [10, 200]
    const float* __restrict__ b1,           // [10]
    float* __restrict__ out)                // [32768, 10]
{
    __shared__ __align__(16) char lds_raw[MT * ASTRIDE * 2]; // 45568 B: A / H overlay
    __shared__ __align__(16) float simg[8][SLAB];            // 25600 B: per-wave image slabs
    __hip_bfloat16* A = (__hip_bfloat16*)lds_raw;            // [MT][ASTRIDE] bf16
    float* H = (float*)lds_raw;                              // [MT][HSTRIDE] fp32 (overlays A)

    const int tid  = threadIdx.x;
    const int wave = tid >> 6;
    const int L    = tid & 63;
    const int img0 = blockIdx.x * MT;

    const float k00 = cw[0], k01 = cw[1], k02 = cw[2];
    const float k10 = cw[3], k11 = cw[4], k12 = cw[5];
    const float k20 = cw[6], k21 = cw[7], k22 = cw[8];

    // ---- zero the K pad region (cols 676..711 of each A row) ----
    for (int idx = tid; idx < MT * (ASTRIDE - NPIX); idx += 512) {
        int i = idx / (ASTRIDE - NPIX);
        int c = idx - i * (ASTRIDE - NPIX);
        ((unsigned short*)A)[i * ASTRIDE + NPIX + c] = 0;
    }

    // ---- conv: 4 passes; each pass: wave w stages image 8p+w coalesced -> slab,
    //      then computes conv from slab -> A (bf16, fragment-row layout) ----
    for (int p = 0; p < 4; ++p) {
        const int imgl = p * 8 + wave;
        const float4* src = (const float4*)(x + (size_t)(img0 + imgl) * (IMG * IMG));
        float4* slab4 = (float4*)simg[wave];
        // coalesced stage: 196 float4 over 64 lanes
        slab4[L]       = src[L];
        slab4[L + 64]  = src[L + 64];
        slab4[L + 128] = src[L + 128];
        if (L < 4) slab4[L + 192] = src[L + 192];
        __syncthreads();

        const float* buf = simg[wave];
        unsigned short* abase = (unsigned short*)A + imgl * ASTRIDE;
#pragma unroll
        for (int t = 0; t < 6; ++t) {
            int pp = L + (t << 6);          // output pair index
            if (pp < 338) {
                int p2 = pp * 2;            // first output col index (even)
                int r  = p2 / OHW;
                int c  = p2 - r * OHW;      // even, <= 24
                const float* bp = buf + r * IMG + c;   // 8B aligned
                float2 r0a = *(const float2*)(bp),           r0b = *(const float2*)(bp + 2);
                float2 r1a = *(const float2*)(bp + IMG),     r1b = *(const float2*)(bp + IMG + 2);
                float2 r2a = *(const float2*)(bp + 2 * IMG), r2b = *(const float2*)(bp + 2 * IMG + 2);
                float o0 = r0a.x * k00 + r0a.y * k01 + r0b.x * k02
                         + r1a.x * k10 + r1a.y * k11 + r1b.x * k12
                         + r2a.x * k20 + r2a.y * k21 + r2b.x * k22;
                float o1 = r0a.y * k00 + r0b.x * k01 + r0b.y * k02
                         + r1a.y * k10 + r1b.x * k11 + r1b.y * k12
                         + r2a.y * k20 + r2b.x * k21 + r2b.y * k22;
                unsigned u = (unsigned)bf16_bits(o0) | ((unsigned)bf16_bits(o1) << 16);
                *(unsigned*)(abase + p2) = u;   // p2 even -> dword aligned
            }
        }
        __syncthreads();  // slab reuse + A visibility
    }

    // ---- FC0 via MFMA 16x16x32 bf16 ----
    // 8 waves own disjoint n-tiles {2,2,2,2,2,1,1,1}; each wave does both m-tiles,
    // so every coalesced B-frag load feeds 2 MFMAs.
    const int lm = L & 15;
    const int q  = L >> 4;
    const int ntbase = (wave < 5) ? wave * 2 : 10 + (wave - 5);
    const int ntn    = (wave < 5) ? 2 : 1;

    f32x4 acc[2][2];
#pragma unroll
    for (int m = 0; m < 2; ++m)
#pragma unroll
        for (int t = 0; t < 2; ++t) acc[m][t] = (f32x4){0.f, 0.f, 0.f, 0.f};

    {
        const __hip_bfloat16* a0 = A + lm * ASTRIDE + q * 8;
        const __hip_bfloat16* a1 = A + (16 + lm) * ASTRIDE + q * 8;
        const bf16x8* bb = (const bf16x8*)Bf + (size_t)ntbase * KT_N * 64 + L;

        if (ntn == 2) {
            for (int kt = 0; kt < KT_N; ++kt) {
                bf16x8 af0 = *(const bf16x8*)(a0 + kt * 32);
                bf16x8 af1 = *(const bf16x8*)(a1 + kt * 32);
                bf16x8 bf0 = bb[kt * 64];
                bf16x8 bf1 = bb[(KT_N + kt) * 64];
                acc[0][0] = __builtin_amdgcn_mfma_f32_16x16x32_bf16(af0, bf0, acc[0][0], 0, 0, 0);
                acc[1][0] = __builtin_amdgcn_mfma_f32_16x16x32_bf16(af1, bf0, acc[1][0], 0, 0, 0);
                acc[0][1] = __builtin_amdgcn_mfma_f32_16x16x32_bf16(af0, bf1, acc[0][1], 0, 0, 0);
                acc[1][1] = __builtin_amdgcn_mfma_f32_16x16x32_bf16(af1, bf1, acc[1][1], 0, 0, 0);
            }
        } else {
            for (int kt = 0; kt < KT_N; ++kt) {
                bf16x8 af0 = *(const bf16x8*)(a0 + kt * 32);
                bf16x8 af1 = *(const bf16x8*)(a1 + kt * 32);
                bf16x8 bf0 = bb[kt * 64];
                acc[0][0] = __builtin_amdgcn_mfma_f32_16x16x32_bf16(af0, bf0, acc[0][0], 0, 0, 0);
                acc[1][0] = __builtin_amdgcn_mfma_f32_16x16x32_bf16(af1, bf0, acc[1][0], 0, 0, 0);
            }
        }
    }
    __syncthreads(); // all waves done reading A before H overwrites it

    // ---- epilogue: h = relu(acc + b0) -> LDS ----
#pragma unroll
    for (int t = 0; t < 2; ++t) {
        if (t < ntn) {
            int n = (ntbase + t) * 16 + lm;
            if (n < NH) {
                float bv = b0[n];
#pragma unroll
                for (int m = 0; m < 2; ++m) {
#pragma unroll
                    for (int r = 0; r < 4; ++r) {
                        int mm = m * 16 + q * 4 + r;
                        float v = acc[m][t][r] + bv;
                        H[mm * HSTRIDE + n] = v > 0.f ? v : 0.f;
                    }
                }
            }
        }
    }
    __syncthreads();

    // ---- FC1: out = h @ w1.T + b1 (fp32 VALU, 320 results/block) ----
    if (tid < MT * NOUT) {
        int i = tid / NOUT;
        int j = tid - i * NOUT;
        const float4* hrow = (const float4*)(H + i * HSTRIDE);
        const float4* wrow = (const float4*)(w1 + j * NH);
        float s = b1[j];
        float4 accv = {0.f, 0.f, 0.f, 0.f};
#pragma unroll 10
        for (int n = 0; n < NH / 4; ++n) {
            float4 h4 = hrow[n];
            float4 w4 = wrow[n];
            accv.x += h4.x * w4.x;
            accv.y += h4.y * w4.y;
            accv.z += h4.z * w4.z;
            accv.w += h4.w * w4.w;
        }
        s += (accv.x + accv.y) + (accv.z + accv.w);
        out[(size_t)(img0 + i) * NOUT + j] = s;
    }
}

extern "C" void kernel_launch(void* const* d_in, const int* in_sizes, int n_in,
                              void* d_out, int out_size, void* d_ws, size_t ws_size,
                              hipStream_t stream) {
    const float* x   = (const float*)d_in[0];
    const float* cw  = (const float*)d_in[1];
    const float* w0  = (const float*)d_in[2];
    const float* b0  = (const float*)d_in[3];
    const float* w1  = (const float*)d_in[4];
    const float* b1  = (const float*)d_in[5];
    float* out = (float*)d_out;

    __hip_bfloat16* Bf = (__hip_bfloat16*)d_ws; // 13*22*512*2 = 292,864 B

    const int pack_elems = NT_N * KT_N * 512;
    pack_weights<<<(pack_elems + 255) / 256, 256, 0, stream>>>(w0, Bf);

    fused_mlp_kernel<<<32768 / MT, 512, 0, stream>>>(x, cw, Bf, b0, w1, b1, out);
}

// Round 6
// 187.412 us; speedup vs baseline: 1.3516x; 1.0165x over previous
//
#include <hip/hip_runtime.h>
#include <hip/hip_bf16.h>

#define IMG 28
#define KX 784             // true K = 28*28
#define KT 25              // k-tiles of 32 -> K padded to 800
#define NT 13              // n-tiles of 16 -> N padded to 208
#define NH 200
#define NOUT 10
#define MT 32              // images per block
#define AS 808             // bf16 elems per LDS A row (800 + 8 pad)
#define HSTRIDE 208        // fp32 elems per LDS h row

typedef __attribute__((ext_vector_type(8))) short bf16x8;
typedef __attribute__((ext_vector_type(4))) float f32x4;
typedef __attribute__((ext_vector_type(4))) short s16x4;

static __device__ __forceinline__ unsigned short bf16_bits(float v) {
    __hip_bfloat16 b = __float2bfloat16(v);
    return *(unsigned short*)&b;
}

// --- build W_eff = w0 composed with conv, packed in MFMA fragment order ---
// Bf[nt][kt][lane][j] = W_eff[nt*16+(lane&15)][kt*32+(lane>>4)*8+j], 0-padded.
// W_eff[n][u*28+v] = sum_{i,j} cw[i*3+j] * w0[n*676 + (u-i)*26 + (v-j)] over valid.
__global__ void build_weff(const float* __restrict__ w0, const float* __restrict__ cw,
                           __hip_bfloat16* __restrict__ Bf) {
    int idx = blockIdx.x * blockDim.x + threadIdx.x;
    if (idx >= NT * KT * 512) return;
    int j = idx & 7, L = (idx >> 3) & 63, kt = (idx >> 9) % KT, nt = idx / (KT * 512);
    int n = nt * 16 + (L & 15);
    int k = kt * 32 + ((L >> 4) << 3) + j;
    float acc = 0.f;
    if (n < NH && k < KX) {
        int u = k / IMG, v = k - u * IMG;
#pragma unroll
        for (int i = 0; i < 3; ++i) {
#pragma unroll
            for (int jj = 0; jj < 3; ++jj) {
                int r = u - i, c = v - jj;
                if (r >= 0 && r < 26 && c >= 0 && c < 26)
                    acc += cw[i * 3 + jj] * w0[n * 676 + r * 26 + c];
            }
        }
    }
    Bf[idx] = __float2bfloat16(acc);
}

// FC0 GEMM loop: both m-subs per wave, NTN n-tiles, B software-pipelined.
template <int NTN>
static __device__ __forceinline__ void gemm_loop(
    const __hip_bfloat16* __restrict__ a0p, const __hip_bfloat16* __restrict__ a1p,
    const bf16x8* __restrict__ bb, f32x4 acc[2][2])
{
    bf16x8 bc0 = bb[0];
    bf16x8 bc1 = (NTN == 2) ? bb[KT * 64] : bc0;
    for (int kt = 0; kt < KT; ++kt) {
        bf16x8 bn0 = bc0, bn1 = bc1;
        if (kt < KT - 1) {
            bn0 = bb[(kt + 1) * 64];
            if (NTN == 2) bn1 = bb[(KT + kt + 1) * 64];
        }
        bf16x8 af0 = *(const bf16x8*)(a0p + kt * 32);
        bf16x8 af1 = *(const bf16x8*)(a1p + kt * 32);
        acc[0][0] = __builtin_amdgcn_mfma_f32_16x16x32_bf16(af0, bc0, acc[0][0], 0, 0, 0);
        acc[1][0] = __builtin_amdgcn_mfma_f32_16x16x32_bf16(af1, bc0, acc[1][0], 0, 0, 0);
        if (NTN == 2) {
            acc[0][1] = __builtin_amdgcn_mfma_f32_16x16x32_bf16(af0, bc1, acc[0][1], 0, 0, 0);
            acc[1][1] = __builtin_amdgcn_mfma_f32_16x16x32_bf16(af1, bc1, acc[1][1], 0, 0, 0);
        }
        bc0 = bn0; bc1 = bn1;
    }
}

__global__ __launch_bounds__(512, 6) void gemm_fused_kernel(
    const float* __restrict__ x,            // [32768, 784]
    const __hip_bfloat16* __restrict__ Bf,  // fragment-packed W_eff
    const float* __restrict__ b0,           // [200]
    const float* __restrict__ w1,           // [10, 200]
    const float* __restrict__ b1,           // [10]
    float* __restrict__ out)                // [32768, 10]
{
    __shared__ __align__(16) char lds_raw[MT * AS * 2];  // 51,712 B
    __hip_bfloat16* A = (__hip_bfloat16*)lds_raw;        // [MT][AS] bf16
    float* H = (float*)lds_raw;                          // [MT][HSTRIDE] fp32 overlay

    const int tid  = threadIdx.x;
    const int wave = tid >> 6;
    const int L    = tid & 63;
    const int lm   = L & 15;
    const int q    = L >> 4;
    const int img0 = blockIdx.x * MT;

    // ---- zero K-pad cols 784..799 (one short per thread: 32 rows x 16 cols) ----
    {
        int row = tid >> 4, c = KX + (tid & 15);
        ((unsigned short*)A)[row * AS + c] = 0;
    }

    // ---- stage x -> bf16 LDS A; 13 back-to-back float4 loads per lane ----
    {
        const float4* xx = (const float4*)(x + (size_t)img0 * KX);  // rows contiguous: 196 f4/row
        float4 v[13];
#pragma unroll
        for (int t = 0; t < 13; ++t) {
            int f = tid + 512 * t;
            v[t] = (f < MT * 196) ? xx[f] : (float4){0.f, 0.f, 0.f, 0.f};
        }
#pragma unroll
        for (int t = 0; t < 13; ++t) {
            int f = tid + 512 * t;
            if (f < MT * 196) {
                int row  = f / 196;
                int col4 = f - row * 196;
                s16x4 p;
                p.x = (short)bf16_bits(v[t].x);
                p.y = (short)bf16_bits(v[t].y);
                p.z = (short)bf16_bits(v[t].z);
                p.w = (short)bf16_bits(v[t].w);
                *(s16x4*)(A + row * AS + col4 * 4) = p;
            }
        }
    }
    __syncthreads();

    // ---- FC0: 8 waves own disjoint n-tiles {2,2,2,2,2,1,1,1}, both m-subs each ----
    const int ntbase = (wave < 5) ? wave * 2 : 10 + (wave - 5);
    const int ntn    = (wave < 5) ? 2 : 1;

    f32x4 acc[2][2];
#pragma unroll
    for (int m = 0; m < 2; ++m)
#pragma unroll
        for (int t = 0; t < 2; ++t) acc[m][t] = (f32x4){0.f, 0.f, 0.f, 0.f};

    {
        const __hip_bfloat16* a0p = A + lm * AS + q * 8;
        const __hip_bfloat16* a1p = A + (16 + lm) * AS + q * 8;
        const bf16x8* bb = (const bf16x8*)Bf + (size_t)ntbase * KT * 64 + L;
        if (ntn == 2) gemm_loop<2>(a0p, a1p, bb, acc);
        else          gemm_loop<1>(a0p, a1p, bb, acc);
    }
    __syncthreads();  // done reading A before H overlay

    // ---- epilogue: h = relu(acc + b0) -> LDS ----
#pragma unroll
    for (int t = 0; t < 2; ++t) {
        if (t < ntn) {
            int n = (ntbase + t) * 16 + lm;
            if (n < NH) {
                float bv = b0[n];
#pragma unroll
                for (int m = 0; m < 2; ++m) {
#pragma unroll
                    for (int r = 0; r < 4; ++r) {
                        int mm = m * 16 + q * 4 + r;
                        float v = acc[m][t][r] + bv;
                        H[mm * HSTRIDE + n] = v > 0.f ? v : 0.f;
                    }
                }
            }
        }
    }
    __syncthreads();

    // ---- FC1: out = h @ w1.T + b1 (fp32 VALU, 320 results/block) ----
    if (tid < MT * NOUT) {
        int i = tid / NOUT;
        int j = tid - i * NOUT;
        const float4* hrow = (const float4*)(H + i * HSTRIDE);
        const float4* wrow = (const float4*)(w1 + j * NH);
        float s = b1[j];
        float4 accv = {0.f, 0.f, 0.f, 0.f};
#pragma unroll 10
        for (int n = 0; n < NH / 4; ++n) {
            float4 h4 = hrow[n];
            float4 w4 = wrow[n];
            accv.x += h4.x * w4.x;
            accv.y += h4.y * w4.y;
            accv.z += h4.z * w4.z;
            accv.w += h4.w * w4.w;
        }
        s += (accv.x + accv.y) + (accv.z + accv.w);
        out[(size_t)(img0 + i) * NOUT + j] = s;
    }
}

extern "C" void kernel_launch(void* const* d_in, const int* in_sizes, int n_in,
                              void* d_out, int out_size, void* d_ws, size_t ws_size,
                              hipStream_t stream) {
    const float* x   = (const float*)d_in[0];
    const float* cw  = (const float*)d_in[1];
    const float* w0  = (const float*)d_in[2];
    const float* b0  = (const float*)d_in[3];
    const float* w1  = (const float*)d_in[4];
    const float* b1  = (const float*)d_in[5];
    float* out = (float*)d_out;

    __hip_bfloat16* Bf = (__hip_bfloat16*)d_ws;  // 13*25*512*2 = 332,800 B

    const int pack_elems = NT * KT * 512;
    build_weff<<<(pack_elems + 255) / 256, 256, 0, stream>>>(w0, cw, Bf);

    gemm_fused_kernel<<<32768 / MT, 512, 0, stream>>>(x, Bf, b0, w1, b1, out);
}